// Round 8
// baseline (313.473 us; speedup 1.0000x reference)
//
#include <hip/hip_runtime.h>
#include <cstdint>
#include <cstddef>

#define NEG_SLOPE 0.2f

typedef _Float16 f16x4 __attribute__((ext_vector_type(4)));
typedef _Float16 f16x8 __attribute__((ext_vector_type(8)));
typedef float    f32x4 __attribute__((ext_vector_type(4)));

static __device__ __forceinline__ float leaky(float x){ return x > 0.f ? x : NEG_SLOPE*x; }
// order-preserving float <-> unsigned key (for atomicMax on floats)
static __device__ __forceinline__ unsigned fkey(float f){
  unsigned u = __float_as_uint(f);
  return (u & 0x80000000u) ? ~u : (u | 0x80000000u);
}
static __device__ __forceinline__ float fdecode(unsigned k){
  return __uint_as_float((k & 0x80000000u) ? (k ^ 0x80000000u) : ~k);
}

// ---------------- edge index dtype detection (sampled, single block) ----------------
__global__ __launch_bounds__(256) void k_detect(const unsigned int* __restrict__ w, int E,
                                                int* __restrict__ flag){
  __shared__ int s;
  if (threadIdx.x == 0) s = 0;
  __syncthreads();
  int nz = 0;
  long long total = 2LL * E;
  #pragma unroll
  for (int j = 0; j < 8; ++j){
    long long idx = ((long long)(threadIdx.x * 8 + j) * total) / 2048;
    idx |= 1;
    if (idx < total) nz |= (w[idx] != 0u);
  }
  if (__any(nz) && (threadIdx.x & 63) == 0) atomicOr(&s, 1);
  __syncthreads();
  if (threadIdx.x == 0) *flag = s;     // 1 => int32, 0 => int64
}

// ---------------- histogram of dst (reads edge index directly) ----------------
__global__ __launch_bounds__(256) void k_hist(const void* __restrict__ ei, int E,
                                              const int* __restrict__ flag,
                                              int* __restrict__ cnt){
  int i = blockIdx.x*256 + threadIdx.x;
  if (i >= E) return;
  int d = (*flag) ? ((const int*)ei)[E+i] : (int)((const long long*)ei)[E+i];
  atomicAdd(&cnt[d], 1);
}

// ---------------- CSR build by destination ----------------
// scan1 also zeroes cnt after reading (cnt is reused as the scatter fill counter).
__global__ __launch_bounds__(256) void k_scan1(int* __restrict__ cnt, int* __restrict__ rowptr,
                                               int* __restrict__ bsum, int N){
  __shared__ int s[256];
  int tid = threadIdx.x;
  int base = blockIdx.x*1024 + tid*4;
  int v0=0,v1=0,v2=0,v3=0;
  if (base+0 < N){ v0 = cnt[base+0]; cnt[base+0] = 0; }
  if (base+1 < N){ v1 = cnt[base+1]; cnt[base+1] = 0; }
  if (base+2 < N){ v2 = cnt[base+2]; cnt[base+2] = 0; }
  if (base+3 < N){ v3 = cnt[base+3]; cnt[base+3] = 0; }
  s[tid] = v0+v1+v2+v3;
  __syncthreads();
  for (int offd=1; offd<256; offd<<=1){
    int t = (tid>=offd) ? s[tid-offd] : 0;
    __syncthreads();
    s[tid] += t;
    __syncthreads();
  }
  int run = (tid>0) ? s[tid-1] : 0;
  run += v0; if (base+0 < N) rowptr[base+1] = run;
  run += v1; if (base+1 < N) rowptr[base+2] = run;
  run += v2; if (base+2 < N) rowptr[base+3] = run;
  run += v3; if (base+3 < N) rowptr[base+4] = run;
  if (tid==255) bsum[blockIdx.x] = s[255];
}

__global__ void k_scan2(int* __restrict__ bsum, int nb){
  if (threadIdx.x==0 && blockIdx.x==0){
    int acc=0;
    for (int i=0;i<nb;i++){ int t=bsum[i]; bsum[i]=acc; acc+=t; }
  }
}

__global__ __launch_bounds__(256) void k_scan3(int* __restrict__ rowptr, const int* __restrict__ bsum,
                                               int N){
  int tid = threadIdx.x;
  int base = blockIdx.x*1024 + tid*4;
  int add = bsum[blockIdx.x];
  #pragma unroll
  for (int j=0;j<4;j++){ int idx = base+j; if (idx < N) rowptr[idx+1] += add; }
  if (blockIdx.x==0 && tid==0) rowptr[0] = 0;
}

__global__ __launch_bounds__(256) void k_scatter(const void* __restrict__ ei, int E,
                                                 const int* __restrict__ flag,
                                                 const int* __restrict__ rowptr,
                                                 int* __restrict__ fill, int* __restrict__ csr_src){
  int i = blockIdx.x*256 + threadIdx.x;
  if (i >= E) return;
  int s, d;
  if (*flag){
    const int* p = (const int*)ei;
    s = p[i]; d = p[E+i];
  } else {
    const long long* p = (const long long*)ei;
    s = (int)p[i]; d = (int)p[E+i];
  }
  int pos = rowptr[d] + atomicAdd(&fill[d], 1);
  csr_src[pos] = s;
}

// ---------------- B prep: W[256x256] fp32 -> Bt_hi/Bt_lo[256x256] f16, TRANSPOSED ----------------
__global__ __launch_bounds__(256) void k_prepB(const float* __restrict__ W,
                                               _Float16* __restrict__ Bt_hi, _Float16* __restrict__ Bt_lo){
  int c = blockIdx.x;          // column of W = row of Bt
  int k = threadIdx.x;
  float v = W[k*256 + c];
  _Float16 h = (_Float16)v;
  _Float16 l = (_Float16)(v - (float)h);
  Bt_hi[c*256 + k] = h;
  Bt_lo[c*256 + k] = l;
}

// ---------------- fp16-split MFMA GEMM (32-row LDS tile) + fused alphas + per-head max ----
// xw16[M,256] = f16( A @ W ); as1/ad1[M,4]; gkey[0..3] = per-head global max(as1).
// Block: 32 rows x 256 cols, 4 waves; wave wv owns cols [64wv,64wv+64) == head wv.
// 32KB LDS -> 5 blocks/CU; grid ~1564 blocks -> deep cross-block overlap of stage/compute.
__global__ __launch_bounds__(256) void k_gemm_f16(const float* __restrict__ A,
                                                  const _Float16* __restrict__ Bt_hi,
                                                  const _Float16* __restrict__ Bt_lo,
                                                  const float* __restrict__ a_src,
                                                  const float* __restrict__ a_dst,
                                                  _Float16* __restrict__ xw16,
                                                  float* __restrict__ as1, float* __restrict__ ad1,
                                                  unsigned* __restrict__ gkey,
                                                  int M){
  __shared__ _Float16 As_hi[32*256];   // 16KB, row stride 512B, XOR-swizzled
  __shared__ _Float16 As_lo[32*256];   // 16KB
  int tid = threadIdx.x;
  int bm = blockIdx.x * 32;

  // ---- stage + convert A tile [32][256] fp32 -> f16 hi/lo in LDS (coalesced loads) ----
  {
    int r  = tid >> 3;            // 0..31
    int cb = (tid & 7) << 5;      // 0,32,...,224
    bool ok = (bm + r) < M;
    const float* Ar = A + (size_t)(bm + r)*256 + cb;
    char* bh = (char*)As_hi + r*512;
    char* bl = (char*)As_lo + r*512;
    int sw = (r & 7) << 4;
    #pragma unroll
    for (int j = 0; j < 8; ++j){
      float4 v = ok ? *(const float4*)&Ar[j*4] : make_float4(0.f,0.f,0.f,0.f);
      f16x4 h, l;
      h[0]=(_Float16)v.x; l[0]=(_Float16)(v.x-(float)h[0]);
      h[1]=(_Float16)v.y; l[1]=(_Float16)(v.y-(float)h[1]);
      h[2]=(_Float16)v.z; l[2]=(_Float16)(v.z-(float)h[2]);
      h[3]=(_Float16)v.w; l[3]=(_Float16)(v.w-(float)h[3]);
      int boff = ((cb + j*4) << 1) ^ sw;
      *(f16x4*)(bh + boff) = h;
      *(f16x4*)(bl + boff) = l;
    }
  }
  __syncthreads();

  int lane = tid & 63, wv = tid >> 6;
  int frow = lane & 15;      // A-row / B-col within 16-subtile (also D-col)
  int kg   = lane >> 4;      // k-group 0..3

  f32x4 acc[2][4];
  #pragma unroll
  for (int mi=0;mi<2;++mi)
    #pragma unroll
    for (int ni=0;ni<4;++ni) acc[mi][ni] = (f32x4){0.f,0.f,0.f,0.f};

  #pragma unroll
  for (int ks = 0; ks < 8; ++ks){
    f16x8 a_hi[2], a_lo[2];
    #pragma unroll
    for (int mi=0;mi<2;++mi){
      int row = mi*16 + frow;
      int boff = (row*512 + ks*64 + kg*16) ^ ((row & 7) << 4);
      a_hi[mi] = *(const f16x8*)((const char*)As_hi + boff);
      a_lo[mi] = *(const f16x8*)((const char*)As_lo + boff);
    }
    #pragma unroll
    for (int ni=0;ni<4;++ni){
      size_t bofs = (size_t)(wv*64 + ni*16 + frow)*256 + ks*32 + kg*8;
      f16x8 b_h = *(const f16x8*)(Bt_hi + bofs);
      f16x8 b_l = *(const f16x8*)(Bt_lo + bofs);
      #pragma unroll
      for (int mi=0;mi<2;++mi){
        acc[mi][ni] = __builtin_amdgcn_mfma_f32_16x16x32_f16(a_hi[mi], b_h, acc[mi][ni], 0,0,0);
        acc[mi][ni] = __builtin_amdgcn_mfma_f32_16x16x32_f16(a_hi[mi], b_l, acc[mi][ni], 0,0,0);
        acc[mi][ni] = __builtin_amdgcn_mfma_f32_16x16x32_f16(a_lo[mi], b_h, acc[mi][ni], 0,0,0);
      }
    }
  }

  // ---- epilogue: D col = frow, row = kg*4 + reg. Store xw16 + fused alphas ----
  float sa[4], da[4];
  #pragma unroll
  for (int ni=0;ni<4;++ni){
    sa[ni] = a_src[wv*64 + ni*16 + frow];
    da[ni] = a_dst[wv*64 + ni*16 + frow];
  }
  float wmaxs = -1e30f;
  #pragma unroll
  for (int mi=0;mi<2;++mi){
    #pragma unroll
    for (int reg=0;reg<4;++reg){
      int row = bm + mi*16 + kg*4 + reg;
      bool ok = row < M;
      float s = 0.f, d = 0.f;
      #pragma unroll
      for (int ni=0;ni<4;++ni){
        _Float16 hv = (_Float16)acc[mi][ni][reg];
        if (ok) xw16[(size_t)row*256 + wv*64 + ni*16 + frow] = hv;
        float fv = (float)hv;
        s = fmaf(fv, sa[ni], s);
        d = fmaf(fv, da[ni], d);
      }
      // reduce across frow (16 lanes within the kg group); all lanes get the total
      s += __shfl_xor(s, 1); d += __shfl_xor(d, 1);
      s += __shfl_xor(s, 2); d += __shfl_xor(d, 2);
      s += __shfl_xor(s, 4); d += __shfl_xor(d, 4);
      s += __shfl_xor(s, 8); d += __shfl_xor(d, 8);
      if (ok && frow == 0){
        as1[row*4 + wv] = s;
        ad1[row*4 + wv] = d;
      }
      wmaxs = fmaxf(wmaxs, ok ? s : -1e30f);
    }
  }
  wmaxs = fmaxf(wmaxs, __shfl_xor(wmaxs, 16));
  wmaxs = fmaxf(wmaxs, __shfl_xor(wmaxs, 32));
  if (lane == 0) atomicMax(&gkey[wv], fkey(wmaxs));
}

// ---------------- layer-1 aggregation (f16 gathers) + fused layer-2 projection ----------------
__global__ __launch_bounds__(256) void k_agg1(const int* __restrict__ rowptr, const int* __restrict__ csr_src,
                                              const float* __restrict__ as1, const float* __restrict__ ad1,
                                              const unsigned* __restrict__ gkey,
                                              const _Float16* __restrict__ xw16, const float* __restrict__ b1,
                                              const float* __restrict__ w2,
                                              float* __restrict__ z, int N){
  int wave = threadIdx.x >> 6, lane = threadIdx.x & 63;
  int n = blockIdx.x*4 + wave;
  if (n >= N) return;
  int hd = lane >> 4;
  float ad_h  = ad1[n*4 + hd];
  float as_n  = as1[n*4 + hd];
  float Mh = leaky(fdecode(gkey[hd]) + ad_h);
  float p = __expf(leaky(as_n + ad_h) - Mh);   // self loop
  float denom = p;
  f16x4 sv = *(const f16x4*)&xw16[(size_t)n*256 + lane*4];
  float4 acc;
  acc.x = p*(float)sv[0]; acc.y = p*(float)sv[1]; acc.z = p*(float)sv[2]; acc.w = p*(float)sv[3];
  int r0 = __builtin_amdgcn_readfirstlane(rowptr[n]);
  int r1 = __builtin_amdgcn_readfirstlane(rowptr[n+1]);
  int i = r0;
  for (; i + 4 <= r1; i += 4){
    int s0 = csr_src[i], s1 = csr_src[i+1], s2 = csr_src[i+2], s3 = csr_src[i+3];
    f16x4 w0 = *(const f16x4*)&xw16[(size_t)s0*256 + lane*4];
    f16x4 w1 = *(const f16x4*)&xw16[(size_t)s1*256 + lane*4];
    f16x4 w2v= *(const f16x4*)&xw16[(size_t)s2*256 + lane*4];
    f16x4 w3 = *(const f16x4*)&xw16[(size_t)s3*256 + lane*4];
    float a0 = as1[s0*4 + hd];
    float a1 = as1[s1*4 + hd];
    float a2 = as1[s2*4 + hd];
    float a3 = as1[s3*4 + hd];
    float p0 = __expf(leaky(a0 + ad_h) - Mh);
    float p1 = __expf(leaky(a1 + ad_h) - Mh);
    float p2 = __expf(leaky(a2 + ad_h) - Mh);
    float p3 = __expf(leaky(a3 + ad_h) - Mh);
    denom += (p0 + p1) + (p2 + p3);
    acc.x = fmaf(p3,(float)w3[0], fmaf(p2,(float)w2v[0], fmaf(p1,(float)w1[0], fmaf(p0,(float)w0[0], acc.x))));
    acc.y = fmaf(p3,(float)w3[1], fmaf(p2,(float)w2v[1], fmaf(p1,(float)w1[1], fmaf(p0,(float)w0[1], acc.y))));
    acc.z = fmaf(p3,(float)w3[2], fmaf(p2,(float)w2v[2], fmaf(p1,(float)w1[2], fmaf(p0,(float)w0[2], acc.z))));
    acc.w = fmaf(p3,(float)w3[3], fmaf(p2,(float)w2v[3], fmaf(p1,(float)w1[3], fmaf(p0,(float)w0[3], acc.w))));
  }
  for (; i < r1; ++i){
    int s = csr_src[i];
    f16x4 w = *(const f16x4*)&xw16[(size_t)s*256 + lane*4];
    float a = as1[s*4 + hd];
    float pe = __expf(leaky(a + ad_h) - Mh);
    denom += pe;
    acc.x = fmaf(pe,(float)w[0], acc.x);
    acc.y = fmaf(pe,(float)w[1], acc.y);
    acc.z = fmaf(pe,(float)w[2], acc.z);
    acc.w = fmaf(pe,(float)w[3], acc.w);
  }
  float inv = 1.0f / (denom + 1e-16f);
  float4 bv = *(const float4*)&b1[lane*4];
  float4 o;
  o.x = fmaxf(fmaf(acc.x, inv, bv.x), 0.f);
  o.y = fmaxf(fmaf(acc.y, inv, bv.y), 0.f);
  o.z = fmaxf(fmaf(acc.z, inv, bv.z), 0.f);
  o.w = fmaxf(fmaf(acc.w, inv, bv.w), 0.f);
  // fused layer-2 projection: z[n] = dot(relu(h[n]), w2)
  float4 wv = *(const float4*)&w2[lane*4];
  float d = o.x*wv.x + o.y*wv.y + o.z*wv.z + o.w*wv.w;
  d += __shfl_xor(d, 1);
  d += __shfl_xor(d, 2);
  d += __shfl_xor(d, 4);
  d += __shfl_xor(d, 8);
  d += __shfl_xor(d, 16);
  d += __shfl_xor(d, 32);
  if (lane == 0) z[n] = d;
}

// ---------------- global max/min of z (for one-pass layer-2 softmax bound) ----------------
__global__ __launch_bounds__(256) void k_maxz(const float* __restrict__ z, unsigned* __restrict__ gkey,
                                              int N){
  float mx = -1e30f, mn = -1e30f;   // mn tracks max(-z)
  for (int i = blockIdx.x*256 + threadIdx.x; i < N; i += gridDim.x*256){
    float v = z[i];
    mx = fmaxf(mx, v);
    mn = fmaxf(mn, -v);
  }
  #pragma unroll
  for (int off=1; off<64; off<<=1){
    mx = fmaxf(mx, __shfl_xor(mx, off));
    mn = fmaxf(mn, __shfl_xor(mn, off));
  }
  if ((threadIdx.x & 63) == 0){
    atomicMax(&gkey[4], fkey(mx));
    atomicMax(&gkey[5], fkey(mn));
  }
}

// ---------------- layer-2 aggregation (H=F=1): one pass with global bound ----------------
__global__ __launch_bounds__(256) void k_agg2(const int* __restrict__ rowptr, const int* __restrict__ csr_src,
                                              const float* __restrict__ z,
                                              const unsigned* __restrict__ gkey,
                                              const float* __restrict__ as2p, const float* __restrict__ ad2p,
                                              const float* __restrict__ b2p,
                                              float* __restrict__ out, int N){
  int wave = threadIdx.x >> 6, lane = threadIdx.x & 63;
  int n = blockIdx.x*4 + wave;
  if (n >= N) return;
  float cas = as2p[0], cad = ad2p[0], cb = b2p[0];
  float zmax = fdecode(gkey[4]);
  float zmin = -fdecode(gkey[5]);
  float zn = z[n];
  float adn = cad * zn;
  float bound = (cas >= 0.f) ? cas*zmax : cas*zmin;   // >= cas*z[s] for all s
  float M2 = leaky(bound + adn);                       // >= every e in this segment
  int r0 = __builtin_amdgcn_readfirstlane(rowptr[n]);
  int r1 = __builtin_amdgcn_readfirstlane(rowptr[n+1]);
  float num = 0.f, den = 0.f;
  if (lane == 0){
    float p = __expf(leaky(cas*zn + adn) - M2);        // self loop
    den = p; num = p * zn;
  }
  for (int i = r0 + lane; i < r1; i += 64){
    int s = csr_src[i];
    float zs = z[s];
    float p = __expf(leaky(cas*zs + adn) - M2);
    den += p;
    num = fmaf(p, zs, num);
  }
  num += __shfl_xor(num, 1);  den += __shfl_xor(den, 1);
  num += __shfl_xor(num, 2);  den += __shfl_xor(den, 2);
  num += __shfl_xor(num, 4);  den += __shfl_xor(den, 4);
  num += __shfl_xor(num, 8);  den += __shfl_xor(den, 8);
  num += __shfl_xor(num, 16); den += __shfl_xor(den, 16);
  num += __shfl_xor(num, 32); den += __shfl_xor(den, 32);
  if (lane == 0) out[n] = num / (den + 1e-16f) + cb;
}

// ---------------- launch ----------------
extern "C" void kernel_launch(void* const* d_in, const int* in_sizes, int n_in,
                              void* d_out, int out_size, void* d_ws, size_t ws_size,
                              hipStream_t stream){
  const float* x    = (const float*)d_in[0];
  const void*  ei   = d_in[1];
  const float* w1   = (const float*)d_in[2];
  const float* asw1 = (const float*)d_in[3];
  const float* adw1 = (const float*)d_in[4];
  const float* b1   = (const float*)d_in[5];
  const float* w2   = (const float*)d_in[6];
  const float* as2  = (const float*)d_in[7];
  const float* ad2  = (const float*)d_in[8];
  const float* b2   = (const float*)d_in[9];
  const int N = in_sizes[0] / 256;
  const int E = in_sizes[1] / 2;
  float* out = (float*)d_out;

  char* wsb = (char*)d_ws;
  size_t off = 0;
  auto alloc = [&](size_t bytes) -> void* {
    void* p = wsb + off;
    off = (off + bytes + 255) & ~(size_t)255;
    return p;
  };
  int*       flag    = (int*)      alloc(4);
  unsigned*  gkey    = (unsigned*) alloc(32);       // [0..3] per-head max(as1); [4] max(z); [5] max(-z)
  int*       cnt     = (int*)      alloc((size_t)N*4);   // histogram, then scatter fill counter
  int*       rowptr  = (int*)      alloc((size_t)(N+1)*4);
  int*       bsum    = (int*)      alloc(1024*4);
  int*       csr_src = (int*)      alloc((size_t)E*4);
  _Float16*  Bt_hi   = (_Float16*) alloc((size_t)256*256*2);
  _Float16*  Bt_lo   = (_Float16*) alloc((size_t)256*256*2);
  _Float16*  xw16    = (_Float16*) alloc((size_t)N*256*2);
  float*     as1     = (float*)    alloc((size_t)N*4*4);
  float*     ad1     = (float*)    alloc((size_t)N*4*4);
  float*     z       = (float*)    alloc((size_t)N*4);

  hipMemsetAsync(gkey, 0, 32, stream);
  hipMemsetAsync(cnt,  0, (size_t)N*4, stream);

  int gE = (E + 255) / 256;
  k_detect <<<1, 256, 0, stream>>>((const unsigned int*)ei, E, flag);
  k_hist   <<<gE, 256, 0, stream>>>(ei, E, flag, cnt);
  int nb = (N + 1023) / 1024;
  k_scan1  <<<nb, 256, 0, stream>>>(cnt, rowptr, bsum, N);   // also zeroes cnt
  k_scan2  <<<1, 64, 0, stream>>>(bsum, nb);
  k_scan3  <<<nb, 256, 0, stream>>>(rowptr, bsum, N);
  k_scatter<<<gE, 256, 0, stream>>>(ei, E, flag, rowptr, cnt, csr_src);

  k_prepB   <<<256, 256, 0, stream>>>(w1, Bt_hi, Bt_lo);
  k_gemm_f16<<<(N + 31) / 32, 256, 0, stream>>>(x, Bt_hi, Bt_lo, asw1, adw1,
                                                xw16, as1, ad1, gkey, N);

  int gN4 = (N + 3) / 4;
  k_agg1 <<<gN4, 256, 0, stream>>>(rowptr, csr_src, as1, ad1, gkey, xw16, b1, w2, z, N);
  k_maxz <<<64, 256, 0, stream>>>(z, gkey, N);
  k_agg2 <<<gN4, 256, 0, stream>>>(rowptr, csr_src, z, gkey, as2, ad2, b2, out, N);
}

// Round 9
// 293.189 us; speedup vs baseline: 1.0692x; 1.0692x over previous
//
#include <hip/hip_runtime.h>
#include <cstdint>
#include <cstddef>

#define NEG_SLOPE 0.2f

typedef _Float16 f16x4 __attribute__((ext_vector_type(4)));
typedef _Float16 f16x8 __attribute__((ext_vector_type(8)));
typedef float    f32x4 __attribute__((ext_vector_type(4)));

static __device__ __forceinline__ float leaky(float x){ return x > 0.f ? x : NEG_SLOPE*x; }
// order-preserving float <-> unsigned key (for atomicMax on floats)
static __device__ __forceinline__ unsigned fkey(float f){
  unsigned u = __float_as_uint(f);
  return (u & 0x80000000u) ? ~u : (u | 0x80000000u);
}
static __device__ __forceinline__ float fdecode(unsigned k){
  return __uint_as_float((k & 0x80000000u) ? (k ^ 0x80000000u) : ~k);
}

// ---------------- edge index dtype detection (sampled, single block) ----------------
__global__ __launch_bounds__(256) void k_detect(const unsigned int* __restrict__ w, int E,
                                                int* __restrict__ flag){
  __shared__ int s;
  if (threadIdx.x == 0) s = 0;
  __syncthreads();
  int nz = 0;
  long long total = 2LL * E;
  #pragma unroll
  for (int j = 0; j < 8; ++j){
    long long idx = ((long long)(threadIdx.x * 8 + j) * total) / 2048;
    idx |= 1;
    if (idx < total) nz |= (w[idx] != 0u);
  }
  if (__any(nz) && (threadIdx.x & 63) == 0) atomicOr(&s, 1);
  __syncthreads();
  if (threadIdx.x == 0) *flag = s;     // 1 => int32, 0 => int64
}

// ---------------- histogram of dst (reads edge index directly) ----------------
__global__ __launch_bounds__(256) void k_hist(const void* __restrict__ ei, int E,
                                              const int* __restrict__ flag,
                                              int* __restrict__ cnt){
  int i = blockIdx.x*256 + threadIdx.x;
  if (i >= E) return;
  int d = (*flag) ? ((const int*)ei)[E+i] : (int)((const long long*)ei)[E+i];
  atomicAdd(&cnt[d], 1);
}

// ---------------- CSR build by destination ----------------
// scan1 also zeroes cnt after reading (cnt is reused as the scatter fill counter).
__global__ __launch_bounds__(256) void k_scan1(int* __restrict__ cnt, int* __restrict__ rowptr,
                                               int* __restrict__ bsum, int N){
  __shared__ int s[256];
  int tid = threadIdx.x;
  int base = blockIdx.x*1024 + tid*4;
  int v0=0,v1=0,v2=0,v3=0;
  if (base+0 < N){ v0 = cnt[base+0]; cnt[base+0] = 0; }
  if (base+1 < N){ v1 = cnt[base+1]; cnt[base+1] = 0; }
  if (base+2 < N){ v2 = cnt[base+2]; cnt[base+2] = 0; }
  if (base+3 < N){ v3 = cnt[base+3]; cnt[base+3] = 0; }
  s[tid] = v0+v1+v2+v3;
  __syncthreads();
  for (int offd=1; offd<256; offd<<=1){
    int t = (tid>=offd) ? s[tid-offd] : 0;
    __syncthreads();
    s[tid] += t;
    __syncthreads();
  }
  int run = (tid>0) ? s[tid-1] : 0;
  run += v0; if (base+0 < N) rowptr[base+1] = run;
  run += v1; if (base+1 < N) rowptr[base+2] = run;
  run += v2; if (base+2 < N) rowptr[base+3] = run;
  run += v3; if (base+3 < N) rowptr[base+4] = run;
  if (tid==255) bsum[blockIdx.x] = s[255];
}

__global__ void k_scan2(int* __restrict__ bsum, int nb){
  if (threadIdx.x==0 && blockIdx.x==0){
    int acc=0;
    for (int i=0;i<nb;i++){ int t=bsum[i]; bsum[i]=acc; acc+=t; }
  }
}

__global__ __launch_bounds__(256) void k_scan3(int* __restrict__ rowptr, const int* __restrict__ bsum,
                                               int N){
  int tid = threadIdx.x;
  int base = blockIdx.x*1024 + tid*4;
  int add = bsum[blockIdx.x];
  #pragma unroll
  for (int j=0;j<4;j++){ int idx = base+j; if (idx < N) rowptr[idx+1] += add; }
  if (blockIdx.x==0 && tid==0) rowptr[0] = 0;
}

__global__ __launch_bounds__(256) void k_scatter(const void* __restrict__ ei, int E,
                                                 const int* __restrict__ flag,
                                                 const int* __restrict__ rowptr,
                                                 int* __restrict__ fill, int* __restrict__ csr_src){
  int i = blockIdx.x*256 + threadIdx.x;
  if (i >= E) return;
  int s, d;
  if (*flag){
    const int* p = (const int*)ei;
    s = p[i]; d = p[E+i];
  } else {
    const long long* p = (const long long*)ei;
    s = (int)p[i]; d = (int)p[E+i];
  }
  int pos = rowptr[d] + atomicAdd(&fill[d], 1);
  csr_src[pos] = s;
}

// ---------------- B prep: W[256x256] fp32 -> fragment-major packed f16 hi/lo ----------------
// Bp layout: [nb=col/16][ks=k/32][lane=((k&31)>>3)*16 + (col&15)][8 f16 (k&7)]
// A wave's fragment load is then base + lane*16B -> one contiguous 1KB segment.
__global__ __launch_bounds__(256) void k_prepB(const float* __restrict__ W,
                                               _Float16* __restrict__ Bp_hi, _Float16* __restrict__ Bp_lo){
  int c = blockIdx.x;          // column of W (output col)
  int k = threadIdx.x;         // k index
  float v = W[k*256 + c];
  _Float16 h = (_Float16)v;
  _Float16 l = (_Float16)(v - (float)h);
  int nb   = c >> 4;
  int frow = c & 15;
  int ks   = k >> 5;
  int kg   = (k >> 3) & 3;
  int ke   = k & 7;
  size_t idx = ((size_t)((nb*8 + ks)*64 + kg*16 + frow) << 3) + ke;
  Bp_hi[idx] = h;
  Bp_lo[idx] = l;
}

// ---------------- fp16-split MFMA GEMM (32-row LDS tile, packed-B) + fused alphas ----
// xw16[M,256] = f16( A @ W ); as1/ad1[M,4]; gkey[0..3] = per-head global max(as1).
// Block: 32 rows x 256 cols, 4 waves; wave wv owns cols [64wv,64wv+64) == head wv.
__global__ __launch_bounds__(256) void k_gemm_f16(const float* __restrict__ A,
                                                  const _Float16* __restrict__ Bp_hi,
                                                  const _Float16* __restrict__ Bp_lo,
                                                  const float* __restrict__ a_src,
                                                  const float* __restrict__ a_dst,
                                                  _Float16* __restrict__ xw16,
                                                  float* __restrict__ as1, float* __restrict__ ad1,
                                                  unsigned* __restrict__ gkey,
                                                  int M){
  __shared__ _Float16 As_hi[32*256];   // 16KB, row stride 512B, XOR-swizzled
  __shared__ _Float16 As_lo[32*256];   // 16KB
  int tid = threadIdx.x;
  int bm = blockIdx.x * 32;

  // ---- stage + convert A tile [32][256] fp32 -> f16 hi/lo in LDS (coalesced loads) ----
  {
    int r  = tid >> 3;            // 0..31
    int cb = (tid & 7) << 5;      // 0,32,...,224
    bool ok = (bm + r) < M;
    const float* Ar = A + (size_t)(bm + r)*256 + cb;
    char* bh = (char*)As_hi + r*512;
    char* bl = (char*)As_lo + r*512;
    int sw = (r & 7) << 4;
    #pragma unroll
    for (int j = 0; j < 8; ++j){
      float4 v = ok ? *(const float4*)&Ar[j*4] : make_float4(0.f,0.f,0.f,0.f);
      f16x4 h, l;
      h[0]=(_Float16)v.x; l[0]=(_Float16)(v.x-(float)h[0]);
      h[1]=(_Float16)v.y; l[1]=(_Float16)(v.y-(float)h[1]);
      h[2]=(_Float16)v.z; l[2]=(_Float16)(v.z-(float)h[2]);
      h[3]=(_Float16)v.w; l[3]=(_Float16)(v.w-(float)h[3]);
      int boff = ((cb + j*4) << 1) ^ sw;
      *(f16x4*)(bh + boff) = h;
      *(f16x4*)(bl + boff) = l;
    }
  }
  __syncthreads();

  int lane = tid & 63, wv = tid >> 6;
  int frow = lane & 15;      // A-row / B-col within 16-subtile (also D-col)
  int kg   = lane >> 4;      // k-group 0..3

  f32x4 acc[2][4];
  #pragma unroll
  for (int mi=0;mi<2;++mi)
    #pragma unroll
    for (int ni=0;ni<4;++ni) acc[mi][ni] = (f32x4){0.f,0.f,0.f,0.f};

  #pragma unroll
  for (int ks = 0; ks < 8; ++ks){
    f16x8 a_hi[2], a_lo[2];
    #pragma unroll
    for (int mi=0;mi<2;++mi){
      int row = mi*16 + frow;
      int boff = (row*512 + ks*64 + kg*16) ^ ((row & 7) << 4);
      a_hi[mi] = *(const f16x8*)((const char*)As_hi + boff);
      a_lo[mi] = *(const f16x8*)((const char*)As_lo + boff);
    }
    #pragma unroll
    for (int ni=0;ni<4;++ni){
      // packed fragment-major: contiguous 1KB per wave-load (addr = base + lane*16B)
      size_t bofs = (((size_t)((wv*4 + ni)*8 + ks)) << 9) + ((size_t)lane << 3);
      f16x8 b_h = *(const f16x8*)(Bp_hi + bofs);
      f16x8 b_l = *(const f16x8*)(Bp_lo + bofs);
      #pragma unroll
      for (int mi=0;mi<2;++mi){
        acc[mi][ni] = __builtin_amdgcn_mfma_f32_16x16x32_f16(a_hi[mi], b_h, acc[mi][ni], 0,0,0);
        acc[mi][ni] = __builtin_amdgcn_mfma_f32_16x16x32_f16(a_hi[mi], b_l, acc[mi][ni], 0,0,0);
        acc[mi][ni] = __builtin_amdgcn_mfma_f32_16x16x32_f16(a_lo[mi], b_h, acc[mi][ni], 0,0,0);
      }
    }
  }

  // ---- epilogue: D col = frow, row = kg*4 + reg. Store xw16 + fused alphas ----
  float sa[4], da[4];
  #pragma unroll
  for (int ni=0;ni<4;++ni){
    sa[ni] = a_src[wv*64 + ni*16 + frow];
    da[ni] = a_dst[wv*64 + ni*16 + frow];
  }
  float wmaxs = -1e30f;
  #pragma unroll
  for (int mi=0;mi<2;++mi){
    #pragma unroll
    for (int reg=0;reg<4;++reg){
      int row = bm + mi*16 + kg*4 + reg;
      bool ok = row < M;
      float s = 0.f, d = 0.f;
      #pragma unroll
      for (int ni=0;ni<4;++ni){
        _Float16 hv = (_Float16)acc[mi][ni][reg];
        if (ok) xw16[(size_t)row*256 + wv*64 + ni*16 + frow] = hv;
        float fv = (float)hv;
        s = fmaf(fv, sa[ni], s);
        d = fmaf(fv, da[ni], d);
      }
      // reduce across frow (16 lanes within the kg group); all lanes get the total
      s += __shfl_xor(s, 1); d += __shfl_xor(d, 1);
      s += __shfl_xor(s, 2); d += __shfl_xor(d, 2);
      s += __shfl_xor(s, 4); d += __shfl_xor(d, 4);
      s += __shfl_xor(s, 8); d += __shfl_xor(d, 8);
      if (ok && frow == 0){
        as1[row*4 + wv] = s;
        ad1[row*4 + wv] = d;
      }
      wmaxs = fmaxf(wmaxs, ok ? s : -1e30f);
    }
  }
  wmaxs = fmaxf(wmaxs, __shfl_xor(wmaxs, 16));
  wmaxs = fmaxf(wmaxs, __shfl_xor(wmaxs, 32));
  if (lane == 0) atomicMax(&gkey[wv], fkey(wmaxs));
}

// ---------------- layer-1 aggregation (f16 gathers) + fused layer-2 projection ----------------
__global__ __launch_bounds__(256) void k_agg1(const int* __restrict__ rowptr, const int* __restrict__ csr_src,
                                              const float* __restrict__ as1, const float* __restrict__ ad1,
                                              const unsigned* __restrict__ gkey,
                                              const _Float16* __restrict__ xw16, const float* __restrict__ b1,
                                              const float* __restrict__ w2,
                                              float* __restrict__ z, int N){
  int wave = threadIdx.x >> 6, lane = threadIdx.x & 63;
  int n = blockIdx.x*4 + wave;
  if (n >= N) return;
  int hd = lane >> 4;
  float ad_h  = ad1[n*4 + hd];
  float as_n  = as1[n*4 + hd];
  float Mh = leaky(fdecode(gkey[hd]) + ad_h);
  float p = __expf(leaky(as_n + ad_h) - Mh);   // self loop
  float denom = p;
  f16x4 sv = *(const f16x4*)&xw16[(size_t)n*256 + lane*4];
  float4 acc;
  acc.x = p*(float)sv[0]; acc.y = p*(float)sv[1]; acc.z = p*(float)sv[2]; acc.w = p*(float)sv[3];
  int r0 = __builtin_amdgcn_readfirstlane(rowptr[n]);
  int r1 = __builtin_amdgcn_readfirstlane(rowptr[n+1]);
  int i = r0;
  for (; i + 4 <= r1; i += 4){
    int s0 = csr_src[i], s1 = csr_src[i+1], s2 = csr_src[i+2], s3 = csr_src[i+3];
    f16x4 w0 = *(const f16x4*)&xw16[(size_t)s0*256 + lane*4];
    f16x4 w1 = *(const f16x4*)&xw16[(size_t)s1*256 + lane*4];
    f16x4 w2v= *(const f16x4*)&xw16[(size_t)s2*256 + lane*4];
    f16x4 w3 = *(const f16x4*)&xw16[(size_t)s3*256 + lane*4];
    float a0 = as1[s0*4 + hd];
    float a1 = as1[s1*4 + hd];
    float a2 = as1[s2*4 + hd];
    float a3 = as1[s3*4 + hd];
    float p0 = __expf(leaky(a0 + ad_h) - Mh);
    float p1 = __expf(leaky(a1 + ad_h) - Mh);
    float p2 = __expf(leaky(a2 + ad_h) - Mh);
    float p3 = __expf(leaky(a3 + ad_h) - Mh);
    denom += (p0 + p1) + (p2 + p3);
    acc.x = fmaf(p3,(float)w3[0], fmaf(p2,(float)w2v[0], fmaf(p1,(float)w1[0], fmaf(p0,(float)w0[0], acc.x))));
    acc.y = fmaf(p3,(float)w3[1], fmaf(p2,(float)w2v[1], fmaf(p1,(float)w1[1], fmaf(p0,(float)w0[1], acc.y))));
    acc.z = fmaf(p3,(float)w3[2], fmaf(p2,(float)w2v[2], fmaf(p1,(float)w1[2], fmaf(p0,(float)w0[2], acc.z))));
    acc.w = fmaf(p3,(float)w3[3], fmaf(p2,(float)w2v[3], fmaf(p1,(float)w1[3], fmaf(p0,(float)w0[3], acc.w))));
  }
  for (; i < r1; ++i){
    int s = csr_src[i];
    f16x4 w = *(const f16x4*)&xw16[(size_t)s*256 + lane*4];
    float a = as1[s*4 + hd];
    float pe = __expf(leaky(a + ad_h) - Mh);
    denom += pe;
    acc.x = fmaf(pe,(float)w[0], acc.x);
    acc.y = fmaf(pe,(float)w[1], acc.y);
    acc.z = fmaf(pe,(float)w[2], acc.z);
    acc.w = fmaf(pe,(float)w[3], acc.w);
  }
  float inv = 1.0f / (denom + 1e-16f);
  float4 bv = *(const float4*)&b1[lane*4];
  float4 o;
  o.x = fmaxf(fmaf(acc.x, inv, bv.x), 0.f);
  o.y = fmaxf(fmaf(acc.y, inv, bv.y), 0.f);
  o.z = fmaxf(fmaf(acc.z, inv, bv.z), 0.f);
  o.w = fmaxf(fmaf(acc.w, inv, bv.w), 0.f);
  // fused layer-2 projection: z[n] = dot(relu(h[n]), w2)
  float4 wv = *(const float4*)&w2[lane*4];
  float d = o.x*wv.x + o.y*wv.y + o.z*wv.z + o.w*wv.w;
  d += __shfl_xor(d, 1);
  d += __shfl_xor(d, 2);
  d += __shfl_xor(d, 4);
  d += __shfl_xor(d, 8);
  d += __shfl_xor(d, 16);
  d += __shfl_xor(d, 32);
  if (lane == 0) z[n] = d;
}

// ---------------- global max/min of z (for one-pass layer-2 softmax bound) ----------------
__global__ __launch_bounds__(256) void k_maxz(const float* __restrict__ z, unsigned* __restrict__ gkey,
                                              int N){
  float mx = -1e30f, mn = -1e30f;   // mn tracks max(-z)
  for (int i = blockIdx.x*256 + threadIdx.x; i < N; i += gridDim.x*256){
    float v = z[i];
    mx = fmaxf(mx, v);
    mn = fmaxf(mn, -v);
  }
  #pragma unroll
  for (int off=1; off<64; off<<=1){
    mx = fmaxf(mx, __shfl_xor(mx, off));
    mn = fmaxf(mn, __shfl_xor(mn, off));
  }
  if ((threadIdx.x & 63) == 0){
    atomicMax(&gkey[4], fkey(mx));
    atomicMax(&gkey[5], fkey(mn));
  }
}

// ---------------- layer-2 aggregation (H=F=1): one pass with global bound ----------------
__global__ __launch_bounds__(256) void k_agg2(const int* __restrict__ rowptr, const int* __restrict__ csr_src,
                                              const float* __restrict__ z,
                                              const unsigned* __restrict__ gkey,
                                              const float* __restrict__ as2p, const float* __restrict__ ad2p,
                                              const float* __restrict__ b2p,
                                              float* __restrict__ out, int N){
  int wave = threadIdx.x >> 6, lane = threadIdx.x & 63;
  int n = blockIdx.x*4 + wave;
  if (n >= N) return;
  float cas = as2p[0], cad = ad2p[0], cb = b2p[0];
  float zmax = fdecode(gkey[4]);
  float zmin = -fdecode(gkey[5]);
  float zn = z[n];
  float adn = cad * zn;
  float bound = (cas >= 0.f) ? cas*zmax : cas*zmin;   // >= cas*z[s] for all s
  float M2 = leaky(bound + adn);                       // >= every e in this segment
  int r0 = __builtin_amdgcn_readfirstlane(rowptr[n]);
  int r1 = __builtin_amdgcn_readfirstlane(rowptr[n+1]);
  float num = 0.f, den = 0.f;
  if (lane == 0){
    float p = __expf(leaky(cas*zn + adn) - M2);        // self loop
    den = p; num = p * zn;
  }
  for (int i = r0 + lane; i < r1; i += 64){
    int s = csr_src[i];
    float zs = z[s];
    float p = __expf(leaky(cas*zs + adn) - M2);
    den += p;
    num = fmaf(p, zs, num);
  }
  num += __shfl_xor(num, 1);  den += __shfl_xor(den, 1);
  num += __shfl_xor(num, 2);  den += __shfl_xor(den, 2);
  num += __shfl_xor(num, 4);  den += __shfl_xor(den, 4);
  num += __shfl_xor(num, 8);  den += __shfl_xor(den, 8);
  num += __shfl_xor(num, 16); den += __shfl_xor(den, 16);
  num += __shfl_xor(num, 32); den += __shfl_xor(den, 32);
  if (lane == 0) out[n] = num / (den + 1e-16f) + cb;
}

// ---------------- launch ----------------
extern "C" void kernel_launch(void* const* d_in, const int* in_sizes, int n_in,
                              void* d_out, int out_size, void* d_ws, size_t ws_size,
                              hipStream_t stream){
  const float* x    = (const float*)d_in[0];
  const void*  ei   = d_in[1];
  const float* w1   = (const float*)d_in[2];
  const float* asw1 = (const float*)d_in[3];
  const float* adw1 = (const float*)d_in[4];
  const float* b1   = (const float*)d_in[5];
  const float* w2   = (const float*)d_in[6];
  const float* as2  = (const float*)d_in[7];
  const float* ad2  = (const float*)d_in[8];
  const float* b2   = (const float*)d_in[9];
  const int N = in_sizes[0] / 256;
  const int E = in_sizes[1] / 2;
  float* out = (float*)d_out;

  char* wsb = (char*)d_ws;
  size_t off = 0;
  auto alloc = [&](size_t bytes) -> void* {
    void* p = wsb + off;
    off = (off + bytes + 255) & ~(size_t)255;
    return p;
  };
  int*       flag    = (int*)      alloc(4);
  unsigned*  gkey    = (unsigned*) alloc(32);       // [0..3] per-head max(as1); [4] max(z); [5] max(-z)
  int*       cnt     = (int*)      alloc((size_t)N*4);   // histogram, then scatter fill counter
  int*       rowptr  = (int*)      alloc((size_t)(N+1)*4);
  int*       bsum    = (int*)      alloc(1024*4);
  int*       csr_src = (int*)      alloc((size_t)E*4);
  _Float16*  Bp_hi   = (_Float16*) alloc((size_t)256*256*2);
  _Float16*  Bp_lo   = (_Float16*) alloc((size_t)256*256*2);
  _Float16*  xw16    = (_Float16*) alloc((size_t)N*256*2);
  float*     as1     = (float*)    alloc((size_t)N*4*4);
  float*     ad1     = (float*)    alloc((size_t)N*4*4);
  float*     z       = (float*)    alloc((size_t)N*4);

  hipMemsetAsync(gkey, 0, 32, stream);
  hipMemsetAsync(cnt,  0, (size_t)N*4, stream);

  int gE = (E + 255) / 256;
  k_detect <<<1, 256, 0, stream>>>((const unsigned int*)ei, E, flag);
  k_hist   <<<gE, 256, 0, stream>>>(ei, E, flag, cnt);
  int nb = (N + 1023) / 1024;
  k_scan1  <<<nb, 256, 0, stream>>>(cnt, rowptr, bsum, N);   // also zeroes cnt
  k_scan2  <<<1, 64, 0, stream>>>(bsum, nb);
  k_scan3  <<<nb, 256, 0, stream>>>(rowptr, bsum, N);
  k_scatter<<<gE, 256, 0, stream>>>(ei, E, flag, rowptr, cnt, csr_src);

  k_prepB   <<<256, 256, 0, stream>>>(w1, Bp_hi, Bp_lo);
  k_gemm_f16<<<(N + 31) / 32, 256, 0, stream>>>(x, Bp_hi, Bp_lo, asw1, adw1,
                                                xw16, as1, ad1, gkey, N);

  int gN4 = (N + 3) / 4;
  k_agg1 <<<gN4, 256, 0, stream>>>(rowptr, csr_src, as1, ad1, gkey, xw16, b1, w2, z, N);
  k_maxz <<<64, 256, 0, stream>>>(z, gkey, N);
  k_agg2 <<<gN4, 256, 0, stream>>>(rowptr, csr_src, z, gkey, as2, ad2, b2, out, N);
}

// Round 10
// 256.000 us; speedup vs baseline: 1.2245x; 1.1453x over previous
//
#include <hip/hip_runtime.h>
#include <cstdint>
#include <cstddef>

#define NEG_SLOPE 0.2f

typedef _Float16 f16x4 __attribute__((ext_vector_type(4)));
typedef _Float16 f16x8 __attribute__((ext_vector_type(8)));
typedef float    f32x4 __attribute__((ext_vector_type(4)));

static __device__ __forceinline__ float leaky(float x){ return x > 0.f ? x : NEG_SLOPE*x; }
// order-preserving float <-> unsigned key (for atomicMax on floats)
static __device__ __forceinline__ unsigned fkey(float f){
  unsigned u = __float_as_uint(f);
  return (u & 0x80000000u) ? ~u : (u | 0x80000000u);
}
static __device__ __forceinline__ float fdecode(unsigned k){
  return __uint_as_float((k & 0x80000000u) ? (k ^ 0x80000000u) : ~k);
}

// ---------------- edge index dtype detection (sampled, single block) + gkey init ----------------
__global__ __launch_bounds__(256) void k_detect(const unsigned int* __restrict__ w, int E,
                                                int* __restrict__ flag, unsigned* __restrict__ gkey){
  __shared__ int s;
  if (threadIdx.x == 0) s = 0;
  if (threadIdx.x < 8) gkey[threadIdx.x] = 0u;   // atomicMax identity
  __syncthreads();
  int nz = 0;
  long long total = 2LL * E;
  #pragma unroll
  for (int j = 0; j < 8; ++j){
    long long idx = ((long long)(threadIdx.x * 8 + j) * total) / 2048;
    idx |= 1;
    if (idx < total) nz |= (w[idx] != 0u);
  }
  if (__any(nz) && (threadIdx.x & 63) == 0) atomicOr(&s, 1);
  __syncthreads();
  if (threadIdx.x == 0) *flag = s;     // 1 => int32, 0 => int64
}

// ---------------- histogram of dst (reads edge index directly) ----------------
__global__ __launch_bounds__(256) void k_hist(const void* __restrict__ ei, int E,
                                              const int* __restrict__ flag,
                                              int* __restrict__ cnt){
  int i = blockIdx.x*256 + threadIdx.x;
  if (i >= E) return;
  int d = (*flag) ? ((const int*)ei)[E+i] : (int)((const long long*)ei)[E+i];
  atomicAdd(&cnt[d], 1);
}

// ---------------- CSR build by destination ----------------
// scan1 also zeroes cnt after reading (cnt is reused as the scatter fill counter).
__global__ __launch_bounds__(256) void k_scan1(int* __restrict__ cnt, int* __restrict__ rowptr,
                                               int* __restrict__ bsum, int N){
  __shared__ int s[256];
  int tid = threadIdx.x;
  int base = blockIdx.x*1024 + tid*4;
  int v0=0,v1=0,v2=0,v3=0;
  if (base+0 < N){ v0 = cnt[base+0]; cnt[base+0] = 0; }
  if (base+1 < N){ v1 = cnt[base+1]; cnt[base+1] = 0; }
  if (base+2 < N){ v2 = cnt[base+2]; cnt[base+2] = 0; }
  if (base+3 < N){ v3 = cnt[base+3]; cnt[base+3] = 0; }
  s[tid] = v0+v1+v2+v3;
  __syncthreads();
  for (int offd=1; offd<256; offd<<=1){
    int t = (tid>=offd) ? s[tid-offd] : 0;
    __syncthreads();
    s[tid] += t;
    __syncthreads();
  }
  int run = (tid>0) ? s[tid-1] : 0;
  run += v0; if (base+0 < N) rowptr[base+1] = run;
  run += v1; if (base+1 < N) rowptr[base+2] = run;
  run += v2; if (base+2 < N) rowptr[base+3] = run;
  run += v3; if (base+3 < N) rowptr[base+4] = run;
  if (tid==255) bsum[blockIdx.x] = s[255];
}

// scan3 now computes its block-prefix from bsum directly (scan2 folded in; nb<=64 so it's cheap)
__global__ __launch_bounds__(256) void k_scan3(int* __restrict__ rowptr, const int* __restrict__ bsum,
                                               int N){
  __shared__ int sadd;
  int tid = threadIdx.x;
  if (tid == 0){
    int a = 0;
    for (int i = 0; i < blockIdx.x; ++i) a += bsum[i];
    sadd = a;
  }
  __syncthreads();
  int add = sadd;
  int base = blockIdx.x*1024 + tid*4;
  #pragma unroll
  for (int j=0;j<4;j++){ int idx = base+j; if (idx < N) rowptr[idx+1] += add; }
  if (blockIdx.x==0 && tid==0) rowptr[0] = 0;
}

__global__ __launch_bounds__(256) void k_scatter(const void* __restrict__ ei, int E,
                                                 const int* __restrict__ flag,
                                                 const int* __restrict__ rowptr,
                                                 int* __restrict__ fill, int* __restrict__ csr_src){
  int i = blockIdx.x*256 + threadIdx.x;
  if (i >= E) return;
  int s, d;
  if (*flag){
    const int* p = (const int*)ei;
    s = p[i]; d = p[E+i];
  } else {
    const long long* p = (const long long*)ei;
    s = (int)p[i]; d = (int)p[E+i];
  }
  int pos = rowptr[d] + atomicAdd(&fill[d], 1);
  csr_src[pos] = s;
}

// ---------------- B prep: W[256x256] fp32 -> fragment-major packed f16 ----------------
// Bp layout: [nb=col/16][ks=k/32][lane=((k&31)>>3)*16 + (col&15)][8 f16 (k&7)]
// A wave's fragment load is then base + lane*16B -> one contiguous 1KB segment.
__global__ __launch_bounds__(256) void k_prepB(const float* __restrict__ W,
                                               _Float16* __restrict__ Bp){
  int c = blockIdx.x;          // column of W (output col)
  int k = threadIdx.x;         // k index
  float v = W[k*256 + c];
  int nb   = c >> 4;
  int frow = c & 15;
  int ks   = k >> 5;
  int kg   = (k >> 3) & 3;
  int ke   = k & 7;
  size_t idx = ((size_t)((nb*8 + ks)*64 + kg*16 + frow) << 3) + ke;
  Bp[idx] = (_Float16)v;
}

// ---------------- pure-f16 MFMA GEMM (64-row LDS tile, packed-B, 2-deep prefetch) ----
// xw16[M,256] = f16( A @ W ); as1/ad1[M,4]; gkey[0..3] = per-head global max(as1).
// Block: 64 rows x 256 cols, 4 waves; wave wv owns cols [64wv,64wv+64) == head wv.
__global__ __launch_bounds__(256, 2) void k_gemm_f16(const float* __restrict__ A,
                                                     const _Float16* __restrict__ Bp,
                                                     const float* __restrict__ a_src,
                                                     const float* __restrict__ a_dst,
                                                     _Float16* __restrict__ xw16,
                                                     float* __restrict__ as1, float* __restrict__ ad1,
                                                     unsigned* __restrict__ gkey,
                                                     int M){
  __shared__ _Float16 As[64*256];   // 32KB, row stride 512B, XOR-swizzled
  int tid = threadIdx.x;
  int bm = blockIdx.x * 64;
  int lane = tid & 63, wv = tid >> 6;

  // ---- stage + convert A tile [64][256] fp32 -> f16 in LDS ----
  // wave w covers rows w*16..w*16+15; per row, 64 lanes read 64 consecutive float4 (1KB coalesced)
  {
    #pragma unroll
    for (int jj = 0; jj < 16; ++jj){
      int r  = wv*16 + jj;
      int gr = bm + r;
      float4 v = (gr < M) ? *(const float4*)&A[(size_t)gr*256 + lane*4]
                          : make_float4(0.f,0.f,0.f,0.f);
      f16x4 h;
      h[0]=(_Float16)v.x; h[1]=(_Float16)v.y; h[2]=(_Float16)v.z; h[3]=(_Float16)v.w;
      int boff = (lane << 3) ^ ((r & 7) << 4);
      *(f16x4*)((char*)As + r*512 + boff) = h;
    }
  }
  __syncthreads();

  int frow = lane & 15;      // A-row / B-col within 16-subtile (also D-col)
  int kg   = lane >> 4;      // k-group 0..3

  f32x4 acc[4][4];
  #pragma unroll
  for (int mi=0;mi<4;++mi)
    #pragma unroll
    for (int ni=0;ni<4;++ni) acc[mi][ni] = (f32x4){0.f,0.f,0.f,0.f};

  // packed fragment-major B: contiguous 1KB per wave-load (addr = base + lane*16B)
  const _Float16* Bw = Bp + (((size_t)(wv*4)*8) << 9) + ((size_t)lane << 3);
  auto bload = [&](int ks, int ni)->f16x8 {
    return *(const f16x8*)(Bw + (((size_t)(ni*8 + ks)) << 9));
  };

  f16x8 b0[4], b1[4], b2[4];
  #pragma unroll
  for (int ni=0;ni<4;++ni) b0[ni] = bload(0, ni);
  #pragma unroll
  for (int ni=0;ni<4;++ni) b1[ni] = bload(1, ni);

  #pragma unroll
  for (int ks = 0; ks < 8; ++ks){
    if (ks < 6){
      #pragma unroll
      for (int ni=0;ni<4;++ni) b2[ni] = bload(ks+2, ni);
    }
    f16x8 a[4];
    #pragma unroll
    for (int mi=0;mi<4;++mi){
      int row = mi*16 + frow;
      int boff = (row*512 + ks*64 + kg*16) ^ ((row & 7) << 4);
      a[mi] = *(const f16x8*)((const char*)As + boff);
    }
    #pragma unroll
    for (int ni=0;ni<4;++ni)
      #pragma unroll
      for (int mi=0;mi<4;++mi)
        acc[mi][ni] = __builtin_amdgcn_mfma_f32_16x16x32_f16(a[mi], b0[ni], acc[mi][ni], 0,0,0);
    #pragma unroll
    for (int ni=0;ni<4;++ni){ b0[ni] = b1[ni]; b1[ni] = b2[ni]; }
  }

  // ---- epilogue: D col = frow, row = kg*4 + reg. Store xw16 + fused alphas ----
  float sa[4], da[4];
  #pragma unroll
  for (int ni=0;ni<4;++ni){
    sa[ni] = a_src[wv*64 + ni*16 + frow];
    da[ni] = a_dst[wv*64 + ni*16 + frow];
  }
  float wmaxs = -1e30f;
  #pragma unroll
  for (int mi=0;mi<4;++mi){
    #pragma unroll
    for (int reg=0;reg<4;++reg){
      int row = bm + mi*16 + kg*4 + reg;
      bool ok = row < M;
      float s = 0.f, d = 0.f;
      #pragma unroll
      for (int ni=0;ni<4;++ni){
        _Float16 hv = (_Float16)acc[mi][ni][reg];
        if (ok) xw16[(size_t)row*256 + wv*64 + ni*16 + frow] = hv;
        float fv = (float)hv;
        s = fmaf(fv, sa[ni], s);
        d = fmaf(fv, da[ni], d);
      }
      // reduce across frow (16 lanes within the kg group); all lanes get the total
      s += __shfl_xor(s, 1); d += __shfl_xor(d, 1);
      s += __shfl_xor(s, 2); d += __shfl_xor(d, 2);
      s += __shfl_xor(s, 4); d += __shfl_xor(d, 4);
      s += __shfl_xor(s, 8); d += __shfl_xor(d, 8);
      if (ok && frow == 0){
        as1[row*4 + wv] = s;
        ad1[row*4 + wv] = d;
      }
      wmaxs = fmaxf(wmaxs, ok ? s : -1e30f);
    }
  }
  wmaxs = fmaxf(wmaxs, __shfl_xor(wmaxs, 16));
  wmaxs = fmaxf(wmaxs, __shfl_xor(wmaxs, 32));
  if (lane == 0) atomicMax(&gkey[wv], fkey(wmaxs));
}

// ---------------- layer-1 aggregation (f16 gathers) + fused layer-2 projection ----------------
__global__ __launch_bounds__(256) void k_agg1(const int* __restrict__ rowptr, const int* __restrict__ csr_src,
                                              const float* __restrict__ as1, const float* __restrict__ ad1,
                                              const unsigned* __restrict__ gkey,
                                              const _Float16* __restrict__ xw16, const float* __restrict__ b1,
                                              const float* __restrict__ w2,
                                              float* __restrict__ z, int N){
  int wave = threadIdx.x >> 6, lane = threadIdx.x & 63;
  int n = blockIdx.x*4 + wave;
  if (n >= N) return;
  int hd = lane >> 4;
  float ad_h  = ad1[n*4 + hd];
  float as_n  = as1[n*4 + hd];
  float Mh = leaky(fdecode(gkey[hd]) + ad_h);
  float p = __expf(leaky(as_n + ad_h) - Mh);   // self loop
  float denom = p;
  f16x4 sv = *(const f16x4*)&xw16[(size_t)n*256 + lane*4];
  float4 acc;
  acc.x = p*(float)sv[0]; acc.y = p*(float)sv[1]; acc.z = p*(float)sv[2]; acc.w = p*(float)sv[3];
  int r0 = __builtin_amdgcn_readfirstlane(rowptr[n]);
  int r1 = __builtin_amdgcn_readfirstlane(rowptr[n+1]);
  int i = r0;
  for (; i + 4 <= r1; i += 4){
    int s0 = csr_src[i], s1 = csr_src[i+1], s2 = csr_src[i+2], s3 = csr_src[i+3];
    f16x4 w0 = *(const f16x4*)&xw16[(size_t)s0*256 + lane*4];
    f16x4 w1 = *(const f16x4*)&xw16[(size_t)s1*256 + lane*4];
    f16x4 w2v= *(const f16x4*)&xw16[(size_t)s2*256 + lane*4];
    f16x4 w3 = *(const f16x4*)&xw16[(size_t)s3*256 + lane*4];
    float a0 = as1[s0*4 + hd];
    float a1 = as1[s1*4 + hd];
    float a2 = as1[s2*4 + hd];
    float a3 = as1[s3*4 + hd];
    float p0 = __expf(leaky(a0 + ad_h) - Mh);
    float p1 = __expf(leaky(a1 + ad_h) - Mh);
    float p2 = __expf(leaky(a2 + ad_h) - Mh);
    float p3 = __expf(leaky(a3 + ad_h) - Mh);
    denom += (p0 + p1) + (p2 + p3);
    acc.x = fmaf(p3,(float)w3[0], fmaf(p2,(float)w2v[0], fmaf(p1,(float)w1[0], fmaf(p0,(float)w0[0], acc.x))));
    acc.y = fmaf(p3,(float)w3[1], fmaf(p2,(float)w2v[1], fmaf(p1,(float)w1[1], fmaf(p0,(float)w0[1], acc.y))));
    acc.z = fmaf(p3,(float)w3[2], fmaf(p2,(float)w2v[2], fmaf(p1,(float)w1[2], fmaf(p0,(float)w0[2], acc.z))));
    acc.w = fmaf(p3,(float)w3[3], fmaf(p2,(float)w2v[3], fmaf(p1,(float)w1[3], fmaf(p0,(float)w0[3], acc.w))));
  }
  for (; i < r1; ++i){
    int s = csr_src[i];
    f16x4 w = *(const f16x4*)&xw16[(size_t)s*256 + lane*4];
    float a = as1[s*4 + hd];
    float pe = __expf(leaky(a + ad_h) - Mh);
    denom += pe;
    acc.x = fmaf(pe,(float)w[0], acc.x);
    acc.y = fmaf(pe,(float)w[1], acc.y);
    acc.z = fmaf(pe,(float)w[2], acc.z);
    acc.w = fmaf(pe,(float)w[3], acc.w);
  }
  float inv = 1.0f / (denom + 1e-16f);
  float4 bv = *(const float4*)&b1[lane*4];
  float4 o;
  o.x = fmaxf(fmaf(acc.x, inv, bv.x), 0.f);
  o.y = fmaxf(fmaf(acc.y, inv, bv.y), 0.f);
  o.z = fmaxf(fmaf(acc.z, inv, bv.z), 0.f);
  o.w = fmaxf(fmaf(acc.w, inv, bv.w), 0.f);
  // fused layer-2 projection: z[n] = dot(relu(h[n]), w2)
  float4 wv = *(const float4*)&w2[lane*4];
  float d = o.x*wv.x + o.y*wv.y + o.z*wv.z + o.w*wv.w;
  d += __shfl_xor(d, 1);
  d += __shfl_xor(d, 2);
  d += __shfl_xor(d, 4);
  d += __shfl_xor(d, 8);
  d += __shfl_xor(d, 16);
  d += __shfl_xor(d, 32);
  if (lane == 0) z[n] = d;
}

// ---------------- global max/min of z (for one-pass layer-2 softmax bound) ----------------
__global__ __launch_bounds__(256) void k_maxz(const float* __restrict__ z, unsigned* __restrict__ gkey,
                                              int N){
  float mx = -1e30f, mn = -1e30f;   // mn tracks max(-z)
  for (int i = blockIdx.x*256 + threadIdx.x; i < N; i += gridDim.x*256){
    float v = z[i];
    mx = fmaxf(mx, v);
    mn = fmaxf(mn, -v);
  }
  #pragma unroll
  for (int off=1; off<64; off<<=1){
    mx = fmaxf(mx, __shfl_xor(mx, off));
    mn = fmaxf(mn, __shfl_xor(mn, off));
  }
  if ((threadIdx.x & 63) == 0){
    atomicMax(&gkey[4], fkey(mx));
    atomicMax(&gkey[5], fkey(mn));
  }
}

// ---------------- layer-2 aggregation (H=F=1): one pass with global bound ----------------
__global__ __launch_bounds__(256) void k_agg2(const int* __restrict__ rowptr, const int* __restrict__ csr_src,
                                              const float* __restrict__ z,
                                              const unsigned* __restrict__ gkey,
                                              const float* __restrict__ as2p, const float* __restrict__ ad2p,
                                              const float* __restrict__ b2p,
                                              float* __restrict__ out, int N){
  int wave = threadIdx.x >> 6, lane = threadIdx.x & 63;
  int n = blockIdx.x*4 + wave;
  if (n >= N) return;
  float cas = as2p[0], cad = ad2p[0], cb = b2p[0];
  float zmax = fdecode(gkey[4]);
  float zmin = -fdecode(gkey[5]);
  float zn = z[n];
  float adn = cad * zn;
  float bound = (cas >= 0.f) ? cas*zmax : cas*zmin;   // >= cas*z[s] for all s
  float M2 = leaky(bound + adn);                       // >= every e in this segment
  int r0 = __builtin_amdgcn_readfirstlane(rowptr[n]);
  int r1 = __builtin_amdgcn_readfirstlane(rowptr[n+1]);
  float num = 0.f, den = 0.f;
  if (lane == 0){
    float p = __expf(leaky(cas*zn + adn) - M2);        // self loop
    den = p; num = p * zn;
  }
  for (int i = r0 + lane; i < r1; i += 64){
    int s = csr_src[i];
    float zs = z[s];
    float p = __expf(leaky(cas*zs + adn) - M2);
    den += p;
    num = fmaf(p, zs, num);
  }
  num += __shfl_xor(num, 1);  den += __shfl_xor(den, 1);
  num += __shfl_xor(num, 2);  den += __shfl_xor(den, 2);
  num += __shfl_xor(num, 4);  den += __shfl_xor(den, 4);
  num += __shfl_xor(num, 8);  den += __shfl_xor(den, 8);
  num += __shfl_xor(num, 16); den += __shfl_xor(den, 16);
  num += __shfl_xor(num, 32); den += __shfl_xor(den, 32);
  if (lane == 0) out[n] = num / (den + 1e-16f) + cb;
}

// ---------------- launch ----------------
extern "C" void kernel_launch(void* const* d_in, const int* in_sizes, int n_in,
                              void* d_out, int out_size, void* d_ws, size_t ws_size,
                              hipStream_t stream){
  const float* x    = (const float*)d_in[0];
  const void*  ei   = d_in[1];
  const float* w1   = (const float*)d_in[2];
  const float* asw1 = (const float*)d_in[3];
  const float* adw1 = (const float*)d_in[4];
  const float* b1   = (const float*)d_in[5];
  const float* w2   = (const float*)d_in[6];
  const float* as2  = (const float*)d_in[7];
  const float* ad2  = (const float*)d_in[8];
  const float* b2   = (const float*)d_in[9];
  const int N = in_sizes[0] / 256;
  const int E = in_sizes[1] / 2;
  float* out = (float*)d_out;

  char* wsb = (char*)d_ws;
  size_t off = 0;
  auto alloc = [&](size_t bytes) -> void* {
    void* p = wsb + off;
    off = (off + bytes + 255) & ~(size_t)255;
    return p;
  };
  int*       flag    = (int*)      alloc(4);
  unsigned*  gkey    = (unsigned*) alloc(32);       // [0..3] per-head max(as1); [4] max(z); [5] max(-z)
  int*       cnt     = (int*)      alloc((size_t)N*4);   // histogram, then scatter fill counter
  int*       rowptr  = (int*)      alloc((size_t)(N+1)*4);
  int*       bsum    = (int*)      alloc(1024*4);
  int*       csr_src = (int*)      alloc((size_t)E*4);
  _Float16*  Bp      = (_Float16*) alloc((size_t)256*256*2);
  _Float16*  xw16    = (_Float16*) alloc((size_t)N*256*2);
  float*     as1     = (float*)    alloc((size_t)N*4*4);
  float*     ad1     = (float*)    alloc((size_t)N*4*4);
  float*     z       = (float*)    alloc((size_t)N*4);

  hipMemsetAsync(cnt, 0, (size_t)N*4, stream);

  int gE = (E + 255) / 256;
  k_detect <<<1, 256, 0, stream>>>((const unsigned int*)ei, E, flag, gkey);
  k_hist   <<<gE, 256, 0, stream>>>(ei, E, flag, cnt);
  int nb = (N + 1023) / 1024;
  k_scan1  <<<nb, 256, 0, stream>>>(cnt, rowptr, bsum, N);   // also zeroes cnt
  k_scan3  <<<nb, 256, 0, stream>>>(rowptr, bsum, N);
  k_scatter<<<gE, 256, 0, stream>>>(ei, E, flag, rowptr, cnt, csr_src);

  k_prepB   <<<256, 256, 0, stream>>>(w1, Bp);
  k_gemm_f16<<<(N + 63) / 64, 256, 0, stream>>>(x, Bp, asw1, adw1,
                                                xw16, as1, ad1, gkey, N);

  int gN4 = (N + 3) / 4;
  k_agg1 <<<gN4, 256, 0, stream>>>(rowptr, csr_src, as1, ad1, gkey, xw16, b1, w2, z, N);
  k_maxz <<<64, 256, 0, stream>>>(z, gkey, N);
  k_agg2 <<<gN4, 256, 0, stream>>>(rowptr, csr_src, z, gkey, as2, ad2, b2, out, N);
}